// Round 4
// baseline (69.939 us; speedup 1.0000x reference)
//
#include <hip/hip_runtime.h>
#include <hip/hip_bf16.h>

// comb_filter: out[b,t,l] = window[l] * sum_k conv_w[pitch[b,t], k] * xp[b, t*HOP + l + k]
// xp = x zero-padded by PAD=768 both sides.
// conv_w rows have <=3 nonzero taps -> scan selected row once per block, then <=3 MACs/elem.
// Dtypes (established by R0-R3 forensics): ALL per the reference —
//   x = float32, pitch = int32, conv_w = float32, out = float32.
//   (The "(bf16, ...)" in the harness failure label is a hardcoded template string.)

#define BATCH   2
#define XLEN    192000
#define PADW    768
#define FRAME   3072
#define HOP     384
#define NFFT    1536
#define KW      1537
#define TFRAMES 497
#define MAXTAP  8

__global__ __launch_bounds__(256) void comb_filter_kernel(
        const float* __restrict__ x,
        const int* __restrict__ pitch,
        const float* __restrict__ conv_w,
        float* __restrict__ out) {
    const int bt = blockIdx.x;            // 0 .. BATCH*TFRAMES-1
    const int b  = bt / TFRAMES;
    const int t  = bt - b * TFRAMES;

    __shared__ int   s_ntap;
    __shared__ int   s_tap_k[MAXTAP];
    __shared__ float s_tap_w[MAXTAP];
    if (threadIdx.x == 0) s_ntap = 0;
    __syncthreads();

    const int p = pitch[bt];
    const float* wrow = conv_w + (long)p * KW;
    for (int k = threadIdx.x; k < KW; k += blockDim.x) {
        float w = wrow[k];
        if (w != 0.0f) {
            int slot = atomicAdd(&s_ntap, 1);
            if (slot < MAXTAP) { s_tap_k[slot] = k; s_tap_w[slot] = w; }
        }
    }
    __syncthreads();

    const int nt = min(s_ntap, MAXTAP);
    const long xbase = (long)b * XLEN;
    const int  off0  = t * HOP - PADW;    // x index = off0 + l + k
    const float inv_nfft = 1.0f / (float)NFFT;
    float* orow = out + (long)bt * NFFT;

    for (int l = threadIdx.x; l < NFFT; l += blockDim.x) {
        float acc = 0.0f;
        #pragma unroll 4
        for (int j = 0; j < nt; ++j) {
            int xi = off0 + l + s_tap_k[j];
            float xv = (xi >= 0 && xi < XLEN) ? x[xbase + xi] : 0.0f;
            acc = fmaf(s_tap_w[j], xv, acc);
        }
        float win = 0.5f - 0.5f * cosf(6.283185307179586f * (float)l * inv_nfft);
        orow[l] = acc * win;
    }
}

extern "C" void kernel_launch(void* const* d_in, const int* in_sizes, int n_in,
                              void* d_out, int out_size, void* d_ws, size_t ws_size,
                              hipStream_t stream) {
    const float* x      = (const float*)d_in[0];
    const int*   pitch  = (const int*)d_in[1];
    const float* conv_w = (const float*)d_in[2];
    float*       out    = (float*)d_out;

    dim3 grid(BATCH * TFRAMES);
    dim3 block(256);
    comb_filter_kernel<<<grid, block, 0, stream>>>(x, pitch, conv_w, out);
}

// Round 5
// 65.589 us; speedup vs baseline: 1.0663x; 1.0663x over previous
//
#include <hip/hip_runtime.h>
#include <hip/hip_bf16.h>

// comb_filter: out[b,t,l] = window[l] * sum_k conv_w[pitch[b,t], k] * xp[b, t*HOP + l + k]
// xp = x zero-padded by PAD=768 both sides. conv_w rows have <=3 nonzero taps.
// Dtypes (R0-R3 forensics): x = f32, pitch = i32, conv_w = f32, out = f32.
// R4 passed (absmax 2e-3). This round: LDS-stage x window (float4), vectorized
// float4 output, __cosf window. Kernel time ~5-8us -> ~3us; dur_us is mostly
// harness poison-fill overhead (268MB fills @ 41us visible in rocprof).

#define BATCH   2
#define XLEN    192000
#define PADW    768
#define FRAME   3072
#define HOP     384
#define NFFT    1536
#define KW      1537
#define TFRAMES 497
#define MAXTAP  8
#define SWIN    3072   // staged x window: l (0..1535) + k (0..1536) -> 0..3071

__global__ __launch_bounds__(256) void comb_filter_kernel(
        const float* __restrict__ x,
        const int* __restrict__ pitch,
        const float* __restrict__ conv_w,
        float* __restrict__ out) {
    const int bt = blockIdx.x;            // 0 .. BATCH*TFRAMES-1
    const int b  = bt / TFRAMES;
    const int t  = bt - b * TFRAMES;
    const int tid = threadIdx.x;

    __shared__ float s_x[SWIN];
    __shared__ int   s_ntap;
    __shared__ int   s_tap_k[MAXTAP];
    __shared__ float s_tap_w[MAXTAP];
    if (tid == 0) s_ntap = 0;
    __syncthreads();

    const long xbase = (long)b * XLEN;
    const int  off0  = t * HOP - PADW;    // x index = off0 + (l + k); 16B-aligned base

    // Stage x[off0 .. off0+3071] into LDS with aligned float4 loads; zero OOB.
    for (int v = tid; v < SWIN / 4; v += 256) {   // 3 iterations
        const int base = off0 + v * 4;
        float4 val;
        if (base >= 0 && base + 3 < XLEN) {
            val = *(const float4*)(x + xbase + base);
        } else {
            val.x = (base + 0 >= 0 && base + 0 < XLEN) ? x[xbase + base + 0] : 0.0f;
            val.y = (base + 1 >= 0 && base + 1 < XLEN) ? x[xbase + base + 1] : 0.0f;
            val.z = (base + 2 >= 0 && base + 2 < XLEN) ? x[xbase + base + 2] : 0.0f;
            val.w = (base + 3 >= 0 && base + 3 < XLEN) ? x[xbase + base + 3] : 0.0f;
        }
        *(float4*)(s_x + v * 4) = val;
    }

    // Find the <=3 nonzero taps of the selected weight row (coalesced scan).
    const int p = pitch[bt];
    const float* wrow = conv_w + (long)p * KW;
    for (int k = tid; k < KW; k += 256) {
        float w = wrow[k];
        if (w != 0.0f) {
            int slot = atomicAdd(&s_ntap, 1);
            if (slot < MAXTAP) { s_tap_k[slot] = k; s_tap_w[slot] = w; }
        }
    }
    __syncthreads();

    const int nt = min(s_ntap, MAXTAP);
    const float w2pi = 6.283185307179586f / (float)NFFT;
    float* orow = out + (long)bt * NFFT;

    for (int v = tid; v < NFFT / 4; v += 256) {   // 2 iterations (384 vec elems)
        const int l = v * 4;
        float4 acc = make_float4(0.f, 0.f, 0.f, 0.f);
        #pragma unroll 3
        for (int j = 0; j < nt; ++j) {
            const int   kk = s_tap_k[j];
            const float w  = s_tap_w[j];
            acc.x = fmaf(w, s_x[l + 0 + kk], acc.x);
            acc.y = fmaf(w, s_x[l + 1 + kk], acc.y);
            acc.z = fmaf(w, s_x[l + 2 + kk], acc.z);
            acc.w = fmaf(w, s_x[l + 3 + kk], acc.w);
        }
        acc.x *= 0.5f - 0.5f * __cosf(w2pi * (float)(l + 0));
        acc.y *= 0.5f - 0.5f * __cosf(w2pi * (float)(l + 1));
        acc.z *= 0.5f - 0.5f * __cosf(w2pi * (float)(l + 2));
        acc.w *= 0.5f - 0.5f * __cosf(w2pi * (float)(l + 3));
        *(float4*)(orow + l) = acc;
    }
}

extern "C" void kernel_launch(void* const* d_in, const int* in_sizes, int n_in,
                              void* d_out, int out_size, void* d_ws, size_t ws_size,
                              hipStream_t stream) {
    const float* x      = (const float*)d_in[0];
    const int*   pitch  = (const int*)d_in[1];
    const float* conv_w = (const float*)d_in[2];
    float*       out    = (float*)d_out;

    dim3 grid(BATCH * TFRAMES);
    dim3 block(256);
    comb_filter_kernel<<<grid, block, 0, stream>>>(x, pitch, conv_w, out);
}